// Round 6
// baseline (370.495 us; speedup 1.0000x reference)
//
#include <hip/hip_runtime.h>

#define NSEQ 1024
#define BATCH 8
#define DIMC 768
#define NH 12
#define HD 64
#define SEG 6291456      // N*B*DIM elements per activation tensor
#define WSEG 589824      // DIM*DIM elements per weight

typedef __attribute__((ext_vector_type(4))) float f32x4;
typedef __attribute__((ext_vector_type(8))) short s16x8;
typedef __attribute__((ext_vector_type(8))) __bf16 bf16x8;

// async global->LDS, 16B per lane. LDS dest must be linear lane-order.
#define GLL16(gsrc, ldst) __builtin_amdgcn_global_load_lds( \
    (const __attribute__((address_space(1))) unsigned int*)(const void*)(gsrc), \
    (__attribute__((address_space(3))) unsigned int*)(void*)(ldst), 16, 0, 0)

__device__ __forceinline__ short f2bf(float f) {
  union { float f; unsigned u; } v; v.f = f;
  unsigned r = (v.u + 0x7FFFu + ((v.u >> 16) & 1u)) >> 16;
  return (short)r;
}

// 1-op RNE f32->bf16 via v_cvt_pk_bf16_f32 (low half of dest)
__device__ __forceinline__ short f2bf1(float f) {
  unsigned r;
  asm("v_cvt_pk_bf16_f32 %0, %1, %2" : "=v"(r) : "v"(f), "v"(0.f));
  return (short)r;
}

__device__ __forceinline__ f32x4 mfma16(bf16x8 a, bf16x8 b, f32x4 c) {
  return __builtin_amdgcn_mfma_f32_16x16x32_bf16(a, b, c, 0, 0, 0);
}

// ---------------- fp32 -> bf16 convert (4 tensors per launch) ----------------
__global__ __launch_bounds__(256) void k_cvt4(
    const float* __restrict__ a0, const float* __restrict__ a1,
    const float* __restrict__ a2, const float* __restrict__ a3,
    short* __restrict__ b0, short* __restrict__ b1,
    short* __restrict__ b2, short* __restrict__ b3, int n4) {
  const float* src; short* dst;
  switch (blockIdx.y) {
    case 0: src = a0; dst = b0; break;
    case 1: src = a1; dst = b1; break;
    case 2: src = a2; dst = b2; break;
    default: src = a3; dst = b3; break;
  }
  int i = blockIdx.x * 256 + threadIdx.x;
  if (i >= n4) return;
  float4 f = reinterpret_cast<const float4*>(src)[i];
  short4 o;
  o.x = f2bf(f.x); o.y = f2bf(f.y); o.z = f2bf(f.z); o.w = f2bf(f.w);
  reinterpret_cast<short4*>(dst)[i] = o;
}

// ---------------- input projections (2-phase double-buffered) ----------------
// streams 0,1 (Q,K): write [b,h,n,d]
// streams 2,3 (V,Vi): write TRANSPOSED [b,h,d,n] via LDS transpose epilogue
__global__ __launch_bounds__(256) void k_proj(
    const short* __restrict__ x0, const short* __restrict__ x1,
    const short* __restrict__ x2, const short* __restrict__ x3,
    const short* __restrict__ w0, const short* __restrict__ w1,
    const short* __restrict__ w2, const short* __restrict__ w3,
    short* __restrict__ y0, short* __restrict__ y1,
    short* __restrict__ y2, short* __restrict__ y3) {
  __shared__ __align__(16) short SM[32768];   // As[2] | Bs[2] (64KB); Ts reuses front 32KB
  const int tid = threadIdx.x;
  const int lane = tid & 63;
  const int w = tid >> 6;
  const int wm = w >> 1, wn = w & 1;
  const int mt = blockIdx.x, nt = blockIdx.y, s = blockIdx.z;
  const short *X, *W; short* Y;
  if (s == 0)      { X = x0; W = w0; Y = y0; }
  else if (s == 1) { X = x1; W = w1; Y = y1; }
  else if (s == 2) { X = x2; W = w2; Y = y2; }
  else             { X = x3; W = w3; Y = y3; }

  f32x4 acc[4][4];
#pragma unroll
  for (int mi = 0; mi < 4; ++mi)
#pragma unroll
    for (int ni = 0; ni < 4; ++ni) acc[mi][ni] = (f32x4){0.f, 0.f, 0.f, 0.f};

#define PROJ_STAGE(BUF, KT) do { \
  _Pragma("unroll") for (int ii = 0; ii < 4; ++ii) { \
    int g = ii * 256 + tid; \
    int o = g * 16; \
    int r = o >> 7; \
    int c0 = ((o & 127) ^ ((r & 7) << 4)) >> 1; \
    int m = mt * 128 + r; \
    GLL16(X + ((size_t)((m & 1023) * BATCH + (m >> 10))) * DIMC + (KT) * 64 + c0, \
          (char*)(SM + (BUF) * 8192) + o); \
    GLL16(W + (size_t)(nt * 128 + r) * DIMC + (KT) * 64 + c0, \
          (char*)(SM + 16384 + (BUF) * 8192) + o); \
  } \
} while (0)

  PROJ_STAGE(0, 0);
  __syncthreads();
  int buf = 0;
  for (int kt = 0; kt < 12; ++kt) {
    if (kt < 11) PROJ_STAGE(buf ^ 1, kt + 1);
    const char* As = (const char*)(SM + buf * 8192);
    const char* Bs = (const char*)(SM + 16384 + buf * 8192);
#pragma unroll
    for (int kk = 0; kk < 2; ++kk) {
      bf16x8 a[4], b[4];
      int ce = kk * 32 + (lane >> 4) * 8;
#pragma unroll
      for (int mi = 0; mi < 4; ++mi) {
        int ra = wm * 64 + mi * 16 + (lane & 15);
        int byte = ((ra << 7) + (ce << 1)) ^ ((ra & 7) << 4);
        a[mi] = *(const bf16x8*)(As + byte);
      }
#pragma unroll
      for (int ni = 0; ni < 4; ++ni) {
        int rb = wn * 64 + ni * 16 + (lane & 15);
        int byte = ((rb << 7) + (ce << 1)) ^ ((rb & 7) << 4);
        b[ni] = *(const bf16x8*)(Bs + byte);
      }
#pragma unroll
      for (int mi = 0; mi < 4; ++mi)
#pragma unroll
        for (int ni = 0; ni < 4; ++ni)
          acc[mi][ni] = mfma16(a[mi], b[ni], acc[mi][ni]);
    }
    __syncthreads();
    buf ^= 1;
  }
#undef PROJ_STAGE

  if (s < 2) {
    // direct [b,h,n,d] write
#pragma unroll
    for (int mi = 0; mi < 4; ++mi)
#pragma unroll
      for (int ni = 0; ni < 4; ++ni)
#pragma unroll
        for (int j = 0; j < 4; ++j) {
          int m = mt * 128 + wm * 64 + mi * 16 + (lane >> 4) * 4 + j;
          int dc = nt * 128 + wn * 64 + ni * 16 + (lane & 15);
          int b_ = m >> 10, n_ = m & 1023;
          int h_ = dc >> 6, d_ = dc & 63;
          Y[((size_t)(b_ * NH + h_) * NSEQ + n_) * HD + d_] = f2bf(acc[mi][ni][j]);
        }
  } else {
    // transpose through LDS, write [b,h,d,n] coalesced
    short* Ts = SM;                  // 128 x 128, XOR-swizzled columns
#pragma unroll
    for (int mi = 0; mi < 4; ++mi)
#pragma unroll
      for (int ni = 0; ni < 4; ++ni)
#pragma unroll
        for (int j = 0; j < 4; ++j) {
          int lm = wm * 64 + mi * 16 + (lane >> 4) * 4 + j;
          int ldc = wn * 64 + ni * 16 + (lane & 15);
          int swc = ldc ^ (lm & 126);
          Ts[lm * 128 + swc] = f2bf(acc[mi][ni][j]);
        }
    __syncthreads();
    int l2 = lane * 2;
#pragma unroll 4
    for (int it = 0; it < 32; ++it) {
      int ldc = it * 4 + w;
      short2 pk;
      pk.x = Ts[l2 * 128 + (ldc ^ (l2 & 126))];
      pk.y = Ts[(l2 + 1) * 128 + (ldc ^ ((l2 + 1) & 126))];
      int dc = nt * 128 + ldc;
      int h_ = dc >> 6, d_ = dc & 63;
      int m = mt * 128 + l2;
      int b_ = m >> 10, n_ = m & 1023;
      *(short2*)(Y + ((size_t)(b_ * NH + h_) * HD + d_) * NSEQ + n_) = pk;
    }
  }
}

// ---------------- flash attention v3: K via LDS dbuf, V/Vi direct-to-register ----------------
// K in [b,h,n,d]; V,Vi pre-transposed [b,h,d,n]. Output head-major [b,h,n,d].
__global__ __launch_bounds__(256) void k_attn(
    const short* __restrict__ qh, const short* __restrict__ kh,
    const short* __restrict__ vt, const short* __restrict__ vit,
    short* __restrict__ xo, short* __restrict__ xio) {
  __shared__ __align__(16) short Ks[2][4096];      // 16KB dbuf, swizzled
  __shared__ __align__(16) short Pl[4][2048];      // per-wave P, swizzled (16KB)

  const int tid = threadIdx.x;
  const int lane = tid & 63;
  const int w = tid >> 6;
  // XCD-chunked swizzle: 12 consecutive bh per XCD
  const int blk = blockIdx.x;
  const int virt = (blk & 7) * 96 + (blk >> 3);
  const int bh = virt >> 3;
  const int qt = virt & 7;
  const float CF = 0.125f * 1.44269504f;   // scale * log2(e)

  const short* qbase = qh + ((size_t)bh * NSEQ + qt * 128 + w * 32) * HD;
  bf16x8 qf[2][2];
#pragma unroll
  for (int mi = 0; mi < 2; ++mi)
#pragma unroll
    for (int kq = 0; kq < 2; ++kq)
      qf[mi][kq] = *(const bf16x8*)(qbase + (mi * 16 + (lane & 15)) * HD + kq * 32 + (lane >> 4) * 8);

  bf16x8 onesf;
#pragma unroll
  for (int i = 0; i < 8; ++i) onesf[i] = (__bf16)1.0f;

  f32x4 o_[2][4], oi_[2][4], l_acc[2];
#pragma unroll
  for (int mi = 0; mi < 2; ++mi) {
    l_acc[mi] = (f32x4){0.f, 0.f, 0.f, 0.f};
#pragma unroll
    for (int x = 0; x < 4; ++x) {
      o_[mi][x] = (f32x4){0.f, 0.f, 0.f, 0.f};
      oi_[mi][x] = (f32x4){0.f, 0.f, 0.f, 0.f};
    }
  }

  const short* khb = kh + (size_t)bh * NSEQ * HD;
  const short* vtb = vt + (size_t)bh * NSEQ * HD;    // [d][n]
  const short* vitb = vit + (size_t)bh * NSEQ * HD;
  char* PlW = (char*)&Pl[w][0];

#define ATTN_STAGE(BUF, KT) do { \
  _Pragma("unroll") for (int ii = 0; ii < 2; ++ii) { \
    int g = ii * 256 + tid; \
    int o = g * 16; \
    int r = o >> 7; \
    int c0 = ((o & 127) ^ ((r & 7) << 4)) >> 1; \
    GLL16(khb + (size_t)((KT) * 64 + r) * HD + c0, (char*)&Ks[BUF][0] + o); \
  } \
} while (0)

  ATTN_STAGE(0, 0);
  __syncthreads();
  int buf = 0;
  for (int kt = 0; kt < 16; ++kt) {
    if (kt < 15) ATTN_STAGE(buf ^ 1, kt + 1);
    const char* KsB = (const char*)&Ks[buf][0];

    // V/V_img fragments direct from global -> registers (overlap QK^T below)
    bf16x8 vfr[2][4], vifr[2][4];
#pragma unroll
    for (int kk = 0; kk < 2; ++kk) {
      int co = kk * 32 + (lane >> 4) * 8;
#pragma unroll
      for (int nd = 0; nd < 4; ++nd) {
        size_t off = (size_t)(nd * 16 + (lane & 15)) * NSEQ + kt * 64 + co;
        vfr[kk][nd]  = *(const bf16x8*)(vtb + off);
        vifr[kk][nd] = *(const bf16x8*)(vitb + off);
      }
    }

    // QK^T, per-ni early exp2 + P store
#pragma unroll
    for (int ni = 0; ni < 4; ++ni) {
      f32x4 s0 = (f32x4){0.f, 0.f, 0.f, 0.f};
      f32x4 s1 = (f32x4){0.f, 0.f, 0.f, 0.f};
#pragma unroll
      for (int kk = 0; kk < 2; ++kk) {
        int ce = kk * 32 + (lane >> 4) * 8;
        int rb = ni * 16 + (lane & 15);
        int byte = ((rb << 7) + (ce << 1)) ^ ((rb & 7) << 4);
        bf16x8 kfr = *(const bf16x8*)(KsB + byte);
        s0 = mfma16(qf[0][kk], kfr, s0);
        s1 = mfma16(qf[1][kk], kfr, s1);
      }
#pragma unroll
      for (int j = 0; j < 4; ++j) {
        float p0 = exp2f(s0[j] * CF);
        float p1 = exp2f(s1[j] * CF);
        int rw0 = (lane >> 4) * 4 + j;
        int col = ni * 16 + (lane & 15);
        int b0 = ((rw0 << 7) + (col << 1)) ^ ((rw0 & 7) << 4);
        int b1 = (((rw0 + 16) << 7) + (col << 1)) ^ ((rw0 & 7) << 4);
        *(short*)(PlW + b0) = f2bf1(p0);
        *(short*)(PlW + b1) = f2bf1(p1);
      }
    }

    // O += P V ; O_img += P V_img ; l += P @ ones
#pragma unroll
    for (int kk = 0; kk < 2; ++kk) {
      int co = kk * 32 + (lane >> 4) * 8;
      int r0 = lane & 15;
      int bp0 = ((r0 << 7) + (co << 1)) ^ ((r0 & 7) << 4);
      int bp1 = (((r0 + 16) << 7) + (co << 1)) ^ ((r0 & 7) << 4);
      bf16x8 pa0 = *(const bf16x8*)(PlW + bp0);
      bf16x8 pa1 = *(const bf16x8*)(PlW + bp1);
      l_acc[0] = mfma16(pa0, onesf, l_acc[0]);
      l_acc[1] = mfma16(pa1, onesf, l_acc[1]);
#pragma unroll
      for (int nd = 0; nd < 4; ++nd) {
        o_[0][nd] = mfma16(pa0, vfr[kk][nd], o_[0][nd]);
        o_[1][nd] = mfma16(pa1, vfr[kk][nd], o_[1][nd]);
        oi_[0][nd] = mfma16(pa0, vifr[kk][nd], oi_[0][nd]);
        oi_[1][nd] = mfma16(pa1, vifr[kk][nd], oi_[1][nd]);
      }
    }
    __syncthreads();
    buf ^= 1;
  }
#undef ATTN_STAGE

  // epilogue: divide by l, write HEAD-MAJOR [b,h,n,d] bf16 (dense 128B rows)
#pragma unroll
  for (int mi = 0; mi < 2; ++mi)
#pragma unroll
    for (int j = 0; j < 4; ++j) {
      float inv = 1.0f / l_acc[mi][j];
      int n_ = qt * 128 + w * 32 + mi * 16 + (lane >> 4) * 4 + j;
      size_t base = ((size_t)bh * NSEQ + n_) * HD;
#pragma unroll
      for (int nd = 0; nd < 4; ++nd) {
        int d_ = nd * 16 + (lane & 15);
        xo[base + d_] = f2bf1(o_[mi][nd][j] * inv);
        xio[base + d_] = f2bf1(oi_[mi][nd][j] * inv);
      }
    }
}

// ---------------- output projections (2-phase): out = X @ W^T + bias ----------------
// X is head-major [b,h,n,d]; K-tile kt == head kt, so A staging stays contiguous.
__global__ __launch_bounds__(256) void k_outproj(
    const short* __restrict__ xa, const short* __restrict__ xb,
    const short* __restrict__ wa, const short* __restrict__ wb,
    const float* __restrict__ ba, const float* __restrict__ bb,
    float* __restrict__ out) {
  __shared__ __align__(16) short SM[32768];   // As[2] | Bs[2]
  const int tid = threadIdx.x;
  const int lane = tid & 63;
  const int w = tid >> 6;
  const int wm = w >> 1, wn = w & 1;
  const int mt = blockIdx.x, nt = blockIdx.y, s = blockIdx.z;
  const short* X = (s == 0) ? xa : xb;
  const short* W = (s == 0) ? wa : wb;
  const float* bias = (s == 0) ? ba : bb;
  float* O = out + (size_t)s * SEG;

  f32x4 acc[4][4];
#pragma unroll
  for (int mi = 0; mi < 4; ++mi)
#pragma unroll
    for (int ni = 0; ni < 4; ++ni) acc[mi][ni] = (f32x4){0.f, 0.f, 0.f, 0.f};

#define OUTP_STAGE(BUF, KT) do { \
  _Pragma("unroll") for (int ii = 0; ii < 4; ++ii) { \
    int g = ii * 256 + tid; \
    int o = g * 16; \
    int r = o >> 7; \
    int c0 = ((o & 127) ^ ((r & 7) << 4)) >> 1; \
    int m = mt * 128 + r; \
    GLL16(X + (((size_t)(m >> 10) * NH + (KT)) * NSEQ + (m & 1023)) * HD + c0, \
          (char*)(SM + (BUF) * 8192) + o); \
    GLL16(W + (size_t)(nt * 128 + r) * DIMC + (KT) * 64 + c0, \
          (char*)(SM + 16384 + (BUF) * 8192) + o); \
  } \
} while (0)

  OUTP_STAGE(0, 0);
  __syncthreads();
  int buf = 0;
  for (int kt = 0; kt < 12; ++kt) {
    if (kt < 11) OUTP_STAGE(buf ^ 1, kt + 1);
    const char* As = (const char*)(SM + buf * 8192);
    const char* Bs = (const char*)(SM + 16384 + buf * 8192);
#pragma unroll
    for (int kk = 0; kk < 2; ++kk) {
      bf16x8 a[4], b[4];
      int ce = kk * 32 + (lane >> 4) * 8;
#pragma unroll
      for (int mi = 0; mi < 4; ++mi) {
        int ra = wm * 64 + mi * 16 + (lane & 15);
        int byte = ((ra << 7) + (ce << 1)) ^ ((ra & 7) << 4);
        a[mi] = *(const bf16x8*)(As + byte);
      }
#pragma unroll
      for (int ni = 0; ni < 4; ++ni) {
        int rb = wn * 64 + ni * 16 + (lane & 15);
        int byte = ((rb << 7) + (ce << 1)) ^ ((rb & 7) << 4);
        b[ni] = *(const bf16x8*)(Bs + byte);
      }
#pragma unroll
      for (int mi = 0; mi < 4; ++mi)
#pragma unroll
        for (int ni = 0; ni < 4; ++ni)
          acc[mi][ni] = mfma16(a[mi], b[ni], acc[mi][ni]);
    }
    __syncthreads();
    buf ^= 1;
  }
#undef OUTP_STAGE

#pragma unroll
  for (int mi = 0; mi < 4; ++mi)
#pragma unroll
    for (int ni = 0; ni < 4; ++ni)
#pragma unroll
      for (int j = 0; j < 4; ++j) {
        int m = mt * 128 + wm * 64 + mi * 16 + (lane >> 4) * 4 + j;
        int dc = nt * 128 + wn * 64 + ni * 16 + (lane & 15);
        O[(size_t)m * DIMC + dc] = acc[mi][ni][j] + bias[dc];
      }
}

extern "C" void kernel_launch(void* const* d_in, const int* in_sizes, int n_in,
                              void* d_out, int out_size, void* d_ws, size_t ws_size,
                              hipStream_t stream) {
  (void)in_sizes; (void)n_in; (void)out_size; (void)ws_size;
  const float* q    = (const float*)d_in[0];
  const float* k    = (const float*)d_in[1];
  const float* v    = (const float*)d_in[2];
  const float* vimg = (const float*)d_in[3];
  const float* Wq   = (const float*)d_in[4];
  const float* Wk   = (const float*)d_in[5];
  const float* Wv   = (const float*)d_in[6];
  const float* Wvim = (const float*)d_in[7];
  const float* Wp   = (const float*)d_in[8];
  const float* bp   = (const float*)d_in[9];
  const float* Wpi  = (const float*)d_in[10];
  const float* bpi  = (const float*)d_in[11];

  short* ws = (short*)d_ws;
  short* xq  = ws;
  short* xk  = ws + (size_t)SEG;
  short* xv  = ws + (size_t)2 * SEG;
  short* xvi = ws + (size_t)3 * SEG;
  short* wqb  = ws + (size_t)4 * SEG;
  short* wkb  = wqb + WSEG;
  short* wvb  = wkb + WSEG;
  short* wvib = wvb + WSEG;
  short* wpb  = wvib + WSEG;
  short* wpib = wpb + WSEG;
  short* qh  = ws + (size_t)4 * SEG + 6 * (size_t)WSEG;
  short* kh  = qh + (size_t)SEG;
  short* vht = kh + (size_t)SEG;    // V transposed [b,h,d,n]
  short* viht = vht + (size_t)SEG;  // V_img transposed
  short* xo  = viht + (size_t)SEG;  // attn out, head-major [b,h,n,d]
  short* xio = xo + (size_t)SEG;

  // 1) convert to bf16
  k_cvt4<<<dim3(SEG / 4 / 256, 4), 256, 0, stream>>>(q, k, v, vimg, xq, xk, xv, xvi, SEG / 4);
  k_cvt4<<<dim3(WSEG / 4 / 256, 4), 256, 0, stream>>>(Wq, Wk, Wv, Wvim, wqb, wkb, wvb, wvib, WSEG / 4);
  k_cvt4<<<dim3(WSEG / 4 / 256, 2), 256, 0, stream>>>(Wp, Wpi, Wp, Wpi, wpb, wpib, wpb, wpib, WSEG / 4);

  // 2) input projections: Q,K -> [b,h,n,d]; V,Vi -> [b,h,d,n]
  k_proj<<<dim3(64, 6, 4), 256, 0, stream>>>(xq, xk, xv, xvi, wqb, wkb, wvb, wvib, qh, kh, vht, viht);

  // 3) shared-softmax attention, two value streams -> head-major [b,h,n,d] bf16
  k_attn<<<dim3(768), 256, 0, stream>>>(qh, kh, vht, viht, xo, xio);

  // 4) output projections + bias -> fp32 d_out (x then x_im)
  k_outproj<<<dim3(64, 6, 2), 256, 0, stream>>>(xo, xio, wpb, wpib, bp, bpi, (float*)d_out);
}

// Round 7
// 340.347 us; speedup vs baseline: 1.0886x; 1.0886x over previous
//
#include <hip/hip_runtime.h>

#define NSEQ 1024
#define BATCH 8
#define DIMC 768
#define NH 12
#define HD 64
#define SEG 6291456      // N*B*DIM elements per activation tensor
#define WSEG 589824      // DIM*DIM elements per weight

typedef __attribute__((ext_vector_type(4))) float f32x4;
typedef __attribute__((ext_vector_type(8))) short s16x8;
typedef __attribute__((ext_vector_type(8))) __bf16 bf16x8;

// async global->LDS, 16B per lane. LDS dest must be linear lane-order.
#define GLL16(gsrc, ldst) __builtin_amdgcn_global_load_lds( \
    (const __attribute__((address_space(1))) unsigned int*)(const void*)(gsrc), \
    (__attribute__((address_space(3))) unsigned int*)(void*)(ldst), 16, 0, 0)

__device__ __forceinline__ short f2bf(float f) {
  union { float f; unsigned u; } v; v.f = f;
  unsigned r = (v.u + 0x7FFFu + ((v.u >> 16) & 1u)) >> 16;
  return (short)r;
}

// 1-op RNE f32->bf16 via v_cvt_pk_bf16_f32 (low half of dest)
__device__ __forceinline__ short f2bf1(float f) {
  unsigned r;
  asm("v_cvt_pk_bf16_f32 %0, %1, %2" : "=v"(r) : "v"(f), "v"(0.f));
  return (short)r;
}

__device__ __forceinline__ f32x4 mfma16(bf16x8 a, bf16x8 b, f32x4 c) {
  return __builtin_amdgcn_mfma_f32_16x16x32_bf16(a, b, c, 0, 0, 0);
}

// ---------------- fp32 -> bf16 convert (4 tensors per launch) ----------------
__global__ __launch_bounds__(256) void k_cvt4(
    const float* __restrict__ a0, const float* __restrict__ a1,
    const float* __restrict__ a2, const float* __restrict__ a3,
    short* __restrict__ b0, short* __restrict__ b1,
    short* __restrict__ b2, short* __restrict__ b3, int n4) {
  const float* src; short* dst;
  switch (blockIdx.y) {
    case 0: src = a0; dst = b0; break;
    case 1: src = a1; dst = b1; break;
    case 2: src = a2; dst = b2; break;
    default: src = a3; dst = b3; break;
  }
  int i = blockIdx.x * 256 + threadIdx.x;
  if (i >= n4) return;
  float4 f = reinterpret_cast<const float4*>(src)[i];
  short4 o;
  o.x = f2bf(f.x); o.y = f2bf(f.y); o.z = f2bf(f.z); o.w = f2bf(f.w);
  reinterpret_cast<short4*>(dst)[i] = o;
}

// ---------------- input projections (2-phase double-buffered) ----------------
// GRID: (nt=6, mt=64, s=4) — consecutive blocks share the A-tile (L2 reuse).
// streams 0,1 (Q,K): write [b,h,n,d]
// streams 2,3 (V,Vi): write TRANSPOSED [b,h,d,n] via LDS transpose epilogue
__global__ __launch_bounds__(256) void k_proj(
    const short* __restrict__ x0, const short* __restrict__ x1,
    const short* __restrict__ x2, const short* __restrict__ x3,
    const short* __restrict__ w0, const short* __restrict__ w1,
    const short* __restrict__ w2, const short* __restrict__ w3,
    short* __restrict__ y0, short* __restrict__ y1,
    short* __restrict__ y2, short* __restrict__ y3) {
  __shared__ __align__(16) short SM[32768];   // As[2] | Bs[2] (64KB); Ts reuses front 32KB
  const int tid = threadIdx.x;
  const int lane = tid & 63;
  const int w = tid >> 6;
  const int wm = w >> 1, wn = w & 1;
  const int nt = blockIdx.x, mt = blockIdx.y, s = blockIdx.z;  // swapped for A-reuse
  const short *X, *W; short* Y;
  if (s == 0)      { X = x0; W = w0; Y = y0; }
  else if (s == 1) { X = x1; W = w1; Y = y1; }
  else if (s == 2) { X = x2; W = w2; Y = y2; }
  else             { X = x3; W = w3; Y = y3; }

  f32x4 acc[4][4];
#pragma unroll
  for (int mi = 0; mi < 4; ++mi)
#pragma unroll
    for (int ni = 0; ni < 4; ++ni) acc[mi][ni] = (f32x4){0.f, 0.f, 0.f, 0.f};

#define PROJ_STAGE(BUF, KT) do { \
  _Pragma("unroll") for (int ii = 0; ii < 4; ++ii) { \
    int g = ii * 256 + tid; \
    int o = g * 16; \
    int r = o >> 7; \
    int c0 = ((o & 127) ^ ((r & 7) << 4)) >> 1; \
    int m = mt * 128 + r; \
    GLL16(X + ((size_t)((m & 1023) * BATCH + (m >> 10))) * DIMC + (KT) * 64 + c0, \
          (char*)(SM + (BUF) * 8192) + o); \
    GLL16(W + (size_t)(nt * 128 + r) * DIMC + (KT) * 64 + c0, \
          (char*)(SM + 16384 + (BUF) * 8192) + o); \
  } \
} while (0)

  PROJ_STAGE(0, 0);
  __syncthreads();
  int buf = 0;
  for (int kt = 0; kt < 12; ++kt) {
    if (kt < 11) PROJ_STAGE(buf ^ 1, kt + 1);
    const char* As = (const char*)(SM + buf * 8192);
    const char* Bs = (const char*)(SM + 16384 + buf * 8192);
#pragma unroll
    for (int kk = 0; kk < 2; ++kk) {
      bf16x8 a[4], b[4];
      int ce = kk * 32 + (lane >> 4) * 8;
#pragma unroll
      for (int mi = 0; mi < 4; ++mi) {
        int ra = wm * 64 + mi * 16 + (lane & 15);
        int byte = ((ra << 7) + (ce << 1)) ^ ((ra & 7) << 4);
        a[mi] = *(const bf16x8*)(As + byte);
      }
#pragma unroll
      for (int ni = 0; ni < 4; ++ni) {
        int rb = wn * 64 + ni * 16 + (lane & 15);
        int byte = ((rb << 7) + (ce << 1)) ^ ((rb & 7) << 4);
        b[ni] = *(const bf16x8*)(Bs + byte);
      }
#pragma unroll
      for (int mi = 0; mi < 4; ++mi)
#pragma unroll
        for (int ni = 0; ni < 4; ++ni)
          acc[mi][ni] = mfma16(a[mi], b[ni], acc[mi][ni]);
    }
    __syncthreads();
    buf ^= 1;
  }
#undef PROJ_STAGE

  if (s < 2) {
    // direct [b,h,n,d] write
#pragma unroll
    for (int mi = 0; mi < 4; ++mi)
#pragma unroll
      for (int ni = 0; ni < 4; ++ni)
#pragma unroll
        for (int j = 0; j < 4; ++j) {
          int m = mt * 128 + wm * 64 + mi * 16 + (lane >> 4) * 4 + j;
          int dc = nt * 128 + wn * 64 + ni * 16 + (lane & 15);
          int b_ = m >> 10, n_ = m & 1023;
          int h_ = dc >> 6, d_ = dc & 63;
          Y[((size_t)(b_ * NH + h_) * NSEQ + n_) * HD + d_] = f2bf(acc[mi][ni][j]);
        }
  } else {
    // transpose through LDS, write [b,h,d,n] coalesced
    __syncthreads();
    short* Ts = SM;                  // 128 x 128, XOR-swizzled columns
#pragma unroll
    for (int mi = 0; mi < 4; ++mi)
#pragma unroll
      for (int ni = 0; ni < 4; ++ni)
#pragma unroll
        for (int j = 0; j < 4; ++j) {
          int lm = wm * 64 + mi * 16 + (lane >> 4) * 4 + j;
          int ldc = wn * 64 + ni * 16 + (lane & 15);
          int swc = ldc ^ (lm & 126);
          Ts[lm * 128 + swc] = f2bf(acc[mi][ni][j]);
        }
    __syncthreads();
    int l2 = lane * 2;
#pragma unroll 4
    for (int it = 0; it < 32; ++it) {
      int ldc = it * 4 + w;
      short2 pk;
      pk.x = Ts[l2 * 128 + (ldc ^ (l2 & 126))];
      pk.y = Ts[(l2 + 1) * 128 + (ldc ^ ((l2 + 1) & 126))];
      int dc = nt * 128 + ldc;
      int h_ = dc >> 6, d_ = dc & 63;
      int m = mt * 128 + l2;
      int b_ = m >> 10, n_ = m & 1023;
      *(short2*)(Y + ((size_t)(b_ * NH + h_) * HD + d_) * NSEQ + n_) = pk;
    }
  }
}

// ---------------- flash attention (R4 structure): K/V/Vi LDS dbuf, fixed-shift softmax ----------------
// K in [b,h,n,d]; V,Vi pre-transposed [b,h,d,n]. Output head-major [b,h,n,d].
__global__ __launch_bounds__(256) void k_attn(
    const short* __restrict__ qh, const short* __restrict__ kh,
    const short* __restrict__ vt, const short* __restrict__ vit,
    short* __restrict__ xo, short* __restrict__ xio) {
  __shared__ __align__(16) short Ks[2][4096];      // 16KB dbuf, swizzled
  __shared__ __align__(16) short Vs[2][4096];      // V^T tiles
  __shared__ __align__(16) short Vis[2][4096];
  __shared__ __align__(16) short Pl[4][2048];      // per-wave P, swizzled (16KB)

  const int tid = threadIdx.x;
  const int lane = tid & 63;
  const int w = tid >> 6;
  // XCD-chunked swizzle: 12 consecutive bh per XCD
  const int blk = blockIdx.x;
  const int virt = (blk & 7) * 96 + (blk >> 3);
  const int bh = virt >> 3;
  const int qt = virt & 7;
  const float CF = 0.125f * 1.44269504f;   // scale * log2(e)

  const short* qbase = qh + ((size_t)bh * NSEQ + qt * 128 + w * 32) * HD;
  bf16x8 qf[2][2];
#pragma unroll
  for (int mi = 0; mi < 2; ++mi)
#pragma unroll
    for (int kq = 0; kq < 2; ++kq)
      qf[mi][kq] = *(const bf16x8*)(qbase + (mi * 16 + (lane & 15)) * HD + kq * 32 + (lane >> 4) * 8);

  bf16x8 onesf;
#pragma unroll
  for (int i = 0; i < 8; ++i) onesf[i] = (__bf16)1.0f;

  f32x4 o_[2][4], oi_[2][4], l_acc[2];
#pragma unroll
  for (int mi = 0; mi < 2; ++mi) {
    l_acc[mi] = (f32x4){0.f, 0.f, 0.f, 0.f};
#pragma unroll
    for (int x = 0; x < 4; ++x) {
      o_[mi][x] = (f32x4){0.f, 0.f, 0.f, 0.f};
      oi_[mi][x] = (f32x4){0.f, 0.f, 0.f, 0.f};
    }
  }

  const short* khb = kh + (size_t)bh * NSEQ * HD;
  const short* vtb = vt + (size_t)bh * NSEQ * HD;    // [d][n]
  const short* vitb = vit + (size_t)bh * NSEQ * HD;
  char* PlW = (char*)&Pl[w][0];

#define ATTN_STAGE(BUF, KT) do { \
  _Pragma("unroll") for (int ii = 0; ii < 2; ++ii) { \
    int g = ii * 256 + tid; \
    int o = g * 16; \
    int r = o >> 7; \
    int c0 = ((o & 127) ^ ((r & 7) << 4)) >> 1; \
    GLL16(khb + (size_t)((KT) * 64 + r) * HD + c0, (char*)&Ks[BUF][0] + o); \
    GLL16(vtb + (size_t)r * NSEQ + (KT) * 64 + c0, (char*)&Vs[BUF][0] + o); \
    GLL16(vitb + (size_t)r * NSEQ + (KT) * 64 + c0, (char*)&Vis[BUF][0] + o); \
  } \
} while (0)

  ATTN_STAGE(0, 0);
  __syncthreads();
  int buf = 0;
  for (int kt = 0; kt < 16; ++kt) {
    if (kt < 15) ATTN_STAGE(buf ^ 1, kt + 1);
    const char* KsB = (const char*)&Ks[buf][0];
    const char* VsB = (const char*)&Vs[buf][0];
    const char* VisB = (const char*)&Vis[buf][0];

    // QK^T, per-ni early exp2 + P store
#pragma unroll
    for (int ni = 0; ni < 4; ++ni) {
      f32x4 s0 = (f32x4){0.f, 0.f, 0.f, 0.f};
      f32x4 s1 = (f32x4){0.f, 0.f, 0.f, 0.f};
#pragma unroll
      for (int kk = 0; kk < 2; ++kk) {
        int ce = kk * 32 + (lane >> 4) * 8;
        int rb = ni * 16 + (lane & 15);
        int byte = ((rb << 7) + (ce << 1)) ^ ((rb & 7) << 4);
        bf16x8 kfr = *(const bf16x8*)(KsB + byte);
        s0 = mfma16(qf[0][kk], kfr, s0);
        s1 = mfma16(qf[1][kk], kfr, s1);
      }
#pragma unroll
      for (int j = 0; j < 4; ++j) {
        float p0 = exp2f(s0[j] * CF);
        float p1 = exp2f(s1[j] * CF);
        int rw0 = (lane >> 4) * 4 + j;
        int col = ni * 16 + (lane & 15);
        int b0 = ((rw0 << 7) + (col << 1)) ^ ((rw0 & 7) << 4);
        int b1 = (((rw0 + 16) << 7) + (col << 1)) ^ ((rw0 & 7) << 4);
        *(short*)(PlW + b0) = f2bf1(p0);
        *(short*)(PlW + b1) = f2bf1(p1);
      }
    }

    // O += P V ; O_img += P V_img ; l += P @ ones
#pragma unroll
    for (int kk = 0; kk < 2; ++kk) {
      int co = kk * 32 + (lane >> 4) * 8;
      int r0 = lane & 15;
      int bp0 = ((r0 << 7) + (co << 1)) ^ ((r0 & 7) << 4);
      int bp1 = (((r0 + 16) << 7) + (co << 1)) ^ ((r0 & 7) << 4);
      bf16x8 pa0 = *(const bf16x8*)(PlW + bp0);
      bf16x8 pa1 = *(const bf16x8*)(PlW + bp1);
      l_acc[0] = mfma16(pa0, onesf, l_acc[0]);
      l_acc[1] = mfma16(pa1, onesf, l_acc[1]);
#pragma unroll
      for (int nd = 0; nd < 4; ++nd) {
        int rv = nd * 16 + (lane & 15);
        int byte = ((rv << 7) + (co << 1)) ^ ((rv & 7) << 4);
        bf16x8 vb = *(const bf16x8*)(VsB + byte);
        bf16x8 vib = *(const bf16x8*)(VisB + byte);
        o_[0][nd] = mfma16(pa0, vb, o_[0][nd]);
        o_[1][nd] = mfma16(pa1, vb, o_[1][nd]);
        oi_[0][nd] = mfma16(pa0, vib, oi_[0][nd]);
        oi_[1][nd] = mfma16(pa1, vib, oi_[1][nd]);
      }
    }
    __syncthreads();
    buf ^= 1;
  }
#undef ATTN_STAGE

  // epilogue: divide by l, write HEAD-MAJOR [b,h,n,d] bf16 (dense 128B rows)
#pragma unroll
  for (int mi = 0; mi < 2; ++mi)
#pragma unroll
    for (int j = 0; j < 4; ++j) {
      float inv = 1.0f / l_acc[mi][j];
      int n_ = qt * 128 + w * 32 + mi * 16 + (lane >> 4) * 4 + j;
      size_t base = ((size_t)bh * NSEQ + n_) * HD;
#pragma unroll
      for (int nd = 0; nd < 4; ++nd) {
        int d_ = nd * 16 + (lane & 15);
        xo[base + d_] = f2bf1(o_[mi][nd][j] * inv);
        xio[base + d_] = f2bf1(oi_[mi][nd][j] * inv);
      }
    }
}

// ---------------- output projections (2-phase): out = X @ W^T + bias ----------------
// GRID: (nt=6, mt=64, s=2) — consecutive blocks share the A-tile (L2 reuse).
// X is head-major [b,h,n,d]; K-tile kt == head kt, so A staging stays contiguous.
__global__ __launch_bounds__(256) void k_outproj(
    const short* __restrict__ xa, const short* __restrict__ xb,
    const short* __restrict__ wa, const short* __restrict__ wb,
    const float* __restrict__ ba, const float* __restrict__ bb,
    float* __restrict__ out) {
  __shared__ __align__(16) short SM[32768];   // As[2] | Bs[2]
  const int tid = threadIdx.x;
  const int lane = tid & 63;
  const int w = tid >> 6;
  const int wm = w >> 1, wn = w & 1;
  const int nt = blockIdx.x, mt = blockIdx.y, s = blockIdx.z;  // swapped for A-reuse
  const short* X = (s == 0) ? xa : xb;
  const short* W = (s == 0) ? wa : wb;
  const float* bias = (s == 0) ? ba : bb;
  float* O = out + (size_t)s * SEG;

  f32x4 acc[4][4];
#pragma unroll
  for (int mi = 0; mi < 4; ++mi)
#pragma unroll
    for (int ni = 0; ni < 4; ++ni) acc[mi][ni] = (f32x4){0.f, 0.f, 0.f, 0.f};

#define OUTP_STAGE(BUF, KT) do { \
  _Pragma("unroll") for (int ii = 0; ii < 4; ++ii) { \
    int g = ii * 256 + tid; \
    int o = g * 16; \
    int r = o >> 7; \
    int c0 = ((o & 127) ^ ((r & 7) << 4)) >> 1; \
    int m = mt * 128 + r; \
    GLL16(X + (((size_t)(m >> 10) * NH + (KT)) * NSEQ + (m & 1023)) * HD + c0, \
          (char*)(SM + (BUF) * 8192) + o); \
    GLL16(W + (size_t)(nt * 128 + r) * DIMC + (KT) * 64 + c0, \
          (char*)(SM + 16384 + (BUF) * 8192) + o); \
  } \
} while (0)

  OUTP_STAGE(0, 0);
  __syncthreads();
  int buf = 0;
  for (int kt = 0; kt < 12; ++kt) {
    if (kt < 11) OUTP_STAGE(buf ^ 1, kt + 1);
    const char* As = (const char*)(SM + buf * 8192);
    const char* Bs = (const char*)(SM + 16384 + buf * 8192);
#pragma unroll
    for (int kk = 0; kk < 2; ++kk) {
      bf16x8 a[4], b[4];
      int ce = kk * 32 + (lane >> 4) * 8;
#pragma unroll
      for (int mi = 0; mi < 4; ++mi) {
        int ra = wm * 64 + mi * 16 + (lane & 15);
        int byte = ((ra << 7) + (ce << 1)) ^ ((ra & 7) << 4);
        a[mi] = *(const bf16x8*)(As + byte);
      }
#pragma unroll
      for (int ni = 0; ni < 4; ++ni) {
        int rb = wn * 64 + ni * 16 + (lane & 15);
        int byte = ((rb << 7) + (ce << 1)) ^ ((rb & 7) << 4);
        b[ni] = *(const bf16x8*)(Bs + byte);
      }
#pragma unroll
      for (int mi = 0; mi < 4; ++mi)
#pragma unroll
        for (int ni = 0; ni < 4; ++ni)
          acc[mi][ni] = mfma16(a[mi], b[ni], acc[mi][ni]);
    }
    __syncthreads();
    buf ^= 1;
  }
#undef OUTP_STAGE

#pragma unroll
  for (int mi = 0; mi < 4; ++mi)
#pragma unroll
    for (int ni = 0; ni < 4; ++ni)
#pragma unroll
      for (int j = 0; j < 4; ++j) {
        int m = mt * 128 + wm * 64 + mi * 16 + (lane >> 4) * 4 + j;
        int dc = nt * 128 + wn * 64 + ni * 16 + (lane & 15);
        O[(size_t)m * DIMC + dc] = acc[mi][ni][j] + bias[dc];
      }
}

extern "C" void kernel_launch(void* const* d_in, const int* in_sizes, int n_in,
                              void* d_out, int out_size, void* d_ws, size_t ws_size,
                              hipStream_t stream) {
  (void)in_sizes; (void)n_in; (void)out_size; (void)ws_size;
  const float* q    = (const float*)d_in[0];
  const float* k    = (const float*)d_in[1];
  const float* v    = (const float*)d_in[2];
  const float* vimg = (const float*)d_in[3];
  const float* Wq   = (const float*)d_in[4];
  const float* Wk   = (const float*)d_in[5];
  const float* Wv   = (const float*)d_in[6];
  const float* Wvim = (const float*)d_in[7];
  const float* Wp   = (const float*)d_in[8];
  const float* bp   = (const float*)d_in[9];
  const float* Wpi  = (const float*)d_in[10];
  const float* bpi  = (const float*)d_in[11];

  short* ws = (short*)d_ws;
  short* xq  = ws;
  short* xk  = ws + (size_t)SEG;
  short* xv  = ws + (size_t)2 * SEG;
  short* xvi = ws + (size_t)3 * SEG;
  short* wqb  = ws + (size_t)4 * SEG;
  short* wkb  = wqb + WSEG;
  short* wvb  = wkb + WSEG;
  short* wvib = wvb + WSEG;
  short* wpb  = wvib + WSEG;
  short* wpib = wpb + WSEG;
  short* qh  = ws + (size_t)4 * SEG + 6 * (size_t)WSEG;
  short* kh  = qh + (size_t)SEG;
  short* vht = kh + (size_t)SEG;    // V transposed [b,h,d,n]
  short* viht = vht + (size_t)SEG;  // V_img transposed
  short* xo  = viht + (size_t)SEG;  // attn out, head-major [b,h,n,d]
  short* xio = xo + (size_t)SEG;

  // 1) convert to bf16
  k_cvt4<<<dim3(SEG / 4 / 256, 4), 256, 0, stream>>>(q, k, v, vimg, xq, xk, xv, xvi, SEG / 4);
  k_cvt4<<<dim3(WSEG / 4 / 256, 4), 256, 0, stream>>>(Wq, Wk, Wv, Wvim, wqb, wkb, wvb, wvib, WSEG / 4);
  k_cvt4<<<dim3(WSEG / 4 / 256, 2), 256, 0, stream>>>(Wp, Wpi, Wp, Wpi, wpb, wpib, wpb, wpib, WSEG / 4);

  // 2) input projections: Q,K -> [b,h,n,d]; V,Vi -> [b,h,d,n]  (grid: nt fastest)
  k_proj<<<dim3(6, 64, 4), 256, 0, stream>>>(xq, xk, xv, xvi, wqb, wkb, wvb, wvib, qh, kh, vht, viht);

  // 3) shared-softmax attention, two value streams -> head-major [b,h,n,d] bf16
  k_attn<<<dim3(768), 256, 0, stream>>>(qh, kh, vht, viht, xo, xio);

  // 4) output projections + bias -> fp32 d_out (x then x_im)  (grid: nt fastest)
  k_outproj<<<dim3(6, 64, 2), 256, 0, stream>>>(xo, xio, wpb, wpib, bp, bpi, (float*)d_out);
}

// Round 8
// 314.138 us; speedup vs baseline: 1.1794x; 1.0834x over previous
//
#include <hip/hip_runtime.h>

#define NSEQ 1024
#define BATCH 8
#define DIMC 768
#define NH 12
#define HD 64
#define SEG 6291456      // N*B*DIM elements per activation tensor
#define WSEG 589824      // DIM*DIM elements per weight

typedef __attribute__((ext_vector_type(4))) float f32x4;
typedef __attribute__((ext_vector_type(4))) unsigned u32x4;
typedef __attribute__((ext_vector_type(8))) short s16x8;
typedef __attribute__((ext_vector_type(8))) __bf16 bf16x8;

// async global->LDS, 16B per lane. LDS dest must be linear lane-order.
#define GLL16(gsrc, ldst) __builtin_amdgcn_global_load_lds( \
    (const __attribute__((address_space(1))) unsigned int*)(const void*)(gsrc), \
    (__attribute__((address_space(3))) unsigned int*)(void*)(ldst), 16, 0, 0)

__device__ __forceinline__ short f2bf(float f) {
  union { float f; unsigned u; } v; v.f = f;
  unsigned r = (v.u + 0x7FFFu + ((v.u >> 16) & 1u)) >> 16;
  return (short)r;
}

// 1-op RNE f32->bf16 via v_cvt_pk_bf16_f32 (low half of dest)
__device__ __forceinline__ short f2bf1(float f) {
  unsigned r;
  asm("v_cvt_pk_bf16_f32 %0, %1, %2" : "=v"(r) : "v"(f), "v"(0.f));
  return (short)r;
}

__device__ __forceinline__ unsigned cvtpk(float lo, float hi) {
  unsigned r;
  asm("v_cvt_pk_bf16_f32 %0, %1, %2" : "=v"(r) : "v"(lo), "v"(hi));
  return r;
}

__device__ __forceinline__ f32x4 mfma16(bf16x8 a, bf16x8 b, f32x4 c) {
  return __builtin_amdgcn_mfma_f32_16x16x32_bf16(a, b, c, 0, 0, 0);
}

// ---------------- fp32 -> bf16 convert (4 tensors per launch, per-tensor scale) ----------------
__global__ __launch_bounds__(256) void k_cvt4(
    const float* __restrict__ a0, const float* __restrict__ a1,
    const float* __restrict__ a2, const float* __restrict__ a3,
    short* __restrict__ b0, short* __restrict__ b1,
    short* __restrict__ b2, short* __restrict__ b3, int n4,
    float s0, float s1, float s2, float s3) {
  const float* src; short* dst; float sc;
  switch (blockIdx.y) {
    case 0: src = a0; dst = b0; sc = s0; break;
    case 1: src = a1; dst = b1; sc = s1; break;
    case 2: src = a2; dst = b2; sc = s2; break;
    default: src = a3; dst = b3; sc = s3; break;
  }
  int i = blockIdx.x * 256 + threadIdx.x;
  if (i >= n4) return;
  float4 f = reinterpret_cast<const float4*>(src)[i];
  short4 o;
  o.x = f2bf(f.x * sc); o.y = f2bf(f.y * sc); o.z = f2bf(f.z * sc); o.w = f2bf(f.w * sc);
  reinterpret_cast<short4*>(dst)[i] = o;
}

// ---------------- input projections (2-phase double-buffered, R4 grid) ----------------
// streams 0,1 (Q,K): write [b,h,n,d]
// streams 2,3 (V,Vi): write TRANSPOSED [b,h,d,n] via LDS transpose epilogue
__global__ __launch_bounds__(256) void k_proj(
    const short* __restrict__ x0, const short* __restrict__ x1,
    const short* __restrict__ x2, const short* __restrict__ x3,
    const short* __restrict__ w0, const short* __restrict__ w1,
    const short* __restrict__ w2, const short* __restrict__ w3,
    short* __restrict__ y0, short* __restrict__ y1,
    short* __restrict__ y2, short* __restrict__ y3) {
  __shared__ __align__(16) short SM[32768];   // As[2] | Bs[2] (64KB); Ts reuses front 32KB
  const int tid = threadIdx.x;
  const int lane = tid & 63;
  const int w = tid >> 6;
  const int wm = w >> 1, wn = w & 1;
  const int mt = blockIdx.x, nt = blockIdx.y, s = blockIdx.z;
  const short *X, *W; short* Y;
  if (s == 0)      { X = x0; W = w0; Y = y0; }
  else if (s == 1) { X = x1; W = w1; Y = y1; }
  else if (s == 2) { X = x2; W = w2; Y = y2; }
  else             { X = x3; W = w3; Y = y3; }

  f32x4 acc[4][4];
#pragma unroll
  for (int mi = 0; mi < 4; ++mi)
#pragma unroll
    for (int ni = 0; ni < 4; ++ni) acc[mi][ni] = (f32x4){0.f, 0.f, 0.f, 0.f};

#define PROJ_STAGE(BUF, KT) do { \
  _Pragma("unroll") for (int ii = 0; ii < 4; ++ii) { \
    int g = ii * 256 + tid; \
    int o = g * 16; \
    int r = o >> 7; \
    int c0 = ((o & 127) ^ ((r & 7) << 4)) >> 1; \
    int m = mt * 128 + r; \
    GLL16(X + ((size_t)((m & 1023) * BATCH + (m >> 10))) * DIMC + (KT) * 64 + c0, \
          (char*)(SM + (BUF) * 8192) + o); \
    GLL16(W + (size_t)(nt * 128 + r) * DIMC + (KT) * 64 + c0, \
          (char*)(SM + 16384 + (BUF) * 8192) + o); \
  } \
} while (0)

  PROJ_STAGE(0, 0);
  __syncthreads();
  int buf = 0;
  for (int kt = 0; kt < 12; ++kt) {
    if (kt < 11) PROJ_STAGE(buf ^ 1, kt + 1);
    const char* As = (const char*)(SM + buf * 8192);
    const char* Bs = (const char*)(SM + 16384 + buf * 8192);
#pragma unroll
    for (int kk = 0; kk < 2; ++kk) {
      bf16x8 a[4], b[4];
      int ce = kk * 32 + (lane >> 4) * 8;
#pragma unroll
      for (int mi = 0; mi < 4; ++mi) {
        int ra = wm * 64 + mi * 16 + (lane & 15);
        int byte = ((ra << 7) + (ce << 1)) ^ ((ra & 7) << 4);
        a[mi] = *(const bf16x8*)(As + byte);
      }
#pragma unroll
      for (int ni = 0; ni < 4; ++ni) {
        int rb = wn * 64 + ni * 16 + (lane & 15);
        int byte = ((rb << 7) + (ce << 1)) ^ ((rb & 7) << 4);
        b[ni] = *(const bf16x8*)(Bs + byte);
      }
#pragma unroll
      for (int mi = 0; mi < 4; ++mi)
#pragma unroll
        for (int ni = 0; ni < 4; ++ni)
          acc[mi][ni] = mfma16(a[mi], b[ni], acc[mi][ni]);
    }
    __syncthreads();
    buf ^= 1;
  }
#undef PROJ_STAGE

  if (s < 2) {
    // direct [b,h,n,d] write
#pragma unroll
    for (int mi = 0; mi < 4; ++mi)
#pragma unroll
      for (int ni = 0; ni < 4; ++ni)
#pragma unroll
        for (int j = 0; j < 4; ++j) {
          int m = mt * 128 + wm * 64 + mi * 16 + (lane >> 4) * 4 + j;
          int dc = nt * 128 + wn * 64 + ni * 16 + (lane & 15);
          int b_ = m >> 10, n_ = m & 1023;
          int h_ = dc >> 6, d_ = dc & 63;
          Y[((size_t)(b_ * NH + h_) * NSEQ + n_) * HD + d_] = f2bf(acc[mi][ni][j]);
        }
  } else {
    // transpose through LDS, write [b,h,d,n] coalesced
    __syncthreads();
    short* Ts = SM;                  // 128 x 128, XOR-swizzled columns
#pragma unroll
    for (int mi = 0; mi < 4; ++mi)
#pragma unroll
      for (int ni = 0; ni < 4; ++ni)
#pragma unroll
        for (int j = 0; j < 4; ++j) {
          int lm = wm * 64 + mi * 16 + (lane >> 4) * 4 + j;
          int ldc = wn * 64 + ni * 16 + (lane & 15);
          int swc = ldc ^ (lm & 126);
          Ts[lm * 128 + swc] = f2bf(acc[mi][ni][j]);
        }
    __syncthreads();
    int l2 = lane * 2;
#pragma unroll 4
    for (int it = 0; it < 32; ++it) {
      int ldc = it * 4 + w;
      short2 pk;
      pk.x = Ts[l2 * 128 + (ldc ^ (l2 & 126))];
      pk.y = Ts[(l2 + 1) * 128 + (ldc ^ ((l2 + 1) & 126))];
      int dc = nt * 128 + ldc;
      int h_ = dc >> 6, d_ = dc & 63;
      int m = mt * 128 + l2;
      int b_ = m >> 10, n_ = m & 1023;
      *(short2*)(Y + ((size_t)(b_ * NH + h_) * HD + d_) * NSEQ + n_) = pk;
    }
  }
}

// ---------------- flash attention v4: swapped QK^T, in-register P via permlane ----------------
// K in [b,h,n,d]; V,Vi pre-transposed [b,h,d,n]. Output head-major [b,h,n,d].
// SCALE*log2e folded into Wq. LDS = 48KB -> 3 blocks/CU, 768 blocks = one pass.
__global__ __launch_bounds__(256) void k_attn(
    const short* __restrict__ qh, const short* __restrict__ kh,
    const short* __restrict__ vt, const short* __restrict__ vit,
    short* __restrict__ xo, short* __restrict__ xio) {
  __shared__ __align__(16) short Ks[2][4096];      // 16KB dbuf, swizzled
  __shared__ __align__(16) short Vs[2][4096];      // V^T tiles
  __shared__ __align__(16) short Vis[2][4096];

  const int tid = threadIdx.x;
  const int lane = tid & 63;
  const int w = tid >> 6;
  // XCD-chunked swizzle: 12 consecutive bh per XCD
  const int blk = blockIdx.x;
  const int virt = (blk & 7) * 96 + (blk >> 3);
  const int bh = virt >> 3;
  const int qt = virt & 7;

  const short* qbase = qh + ((size_t)bh * NSEQ + qt * 128 + w * 32) * HD;
  bf16x8 qf[2][2];
#pragma unroll
  for (int mi = 0; mi < 2; ++mi)
#pragma unroll
    for (int kq = 0; kq < 2; ++kq)
      qf[mi][kq] = *(const bf16x8*)(qbase + (mi * 16 + (lane & 15)) * HD + kq * 32 + (lane >> 4) * 8);

  bf16x8 onesf;
#pragma unroll
  for (int i = 0; i < 8; ++i) onesf[i] = (__bf16)1.0f;

  f32x4 o_[2][4], oi_[2][4], l_acc[2];
#pragma unroll
  for (int mi = 0; mi < 2; ++mi) {
    l_acc[mi] = (f32x4){0.f, 0.f, 0.f, 0.f};
#pragma unroll
    for (int x = 0; x < 4; ++x) {
      o_[mi][x] = (f32x4){0.f, 0.f, 0.f, 0.f};
      oi_[mi][x] = (f32x4){0.f, 0.f, 0.f, 0.f};
    }
  }

  const short* khb = kh + (size_t)bh * NSEQ * HD;
  const short* vtb = vt + (size_t)bh * NSEQ * HD;    // [d][n]
  const short* vitb = vit + (size_t)bh * NSEQ * HD;

#define ATTN_STAGE(BUF, KT) do { \
  _Pragma("unroll") for (int ii = 0; ii < 2; ++ii) { \
    int g = ii * 256 + tid; \
    int o = g * 16; \
    int r = o >> 7; \
    int c0 = ((o & 127) ^ ((r & 7) << 4)) >> 1; \
    GLL16(khb + (size_t)((KT) * 64 + r) * HD + c0, (char*)&Ks[BUF][0] + o); \
    GLL16(vtb + (size_t)r * NSEQ + (KT) * 64 + c0, (char*)&Vs[BUF][0] + o); \
    GLL16(vitb + (size_t)r * NSEQ + (KT) * 64 + c0, (char*)&Vis[BUF][0] + o); \
  } \
} while (0)

  ATTN_STAGE(0, 0);
  __syncthreads();
  int buf = 0;
  for (int kt = 0; kt < 16; ++kt) {
    if (kt < 15) ATTN_STAGE(buf ^ 1, kt + 1);
    const char* KsB = (const char*)&Ks[buf][0];
    const char* VsB = (const char*)&Vs[buf][0];
    const char* VisB = (const char*)&Vis[buf][0];

    // Swapped QK^T: s = mfma(K, Q) -> lane holds P[q=lane&15][k=ni*16+(lane>>4)*4+j]
    // (scale*log2e pre-folded into Wq, so p = exp2(s) directly)
    unsigned pk0[2][4], pk1[2][4];
#pragma unroll
    for (int ni = 0; ni < 4; ++ni) {
      f32x4 s0 = (f32x4){0.f, 0.f, 0.f, 0.f};
      f32x4 s1 = (f32x4){0.f, 0.f, 0.f, 0.f};
#pragma unroll
      for (int kk = 0; kk < 2; ++kk) {
        int ce = kk * 32 + (lane >> 4) * 8;
        int rb = ni * 16 + (lane & 15);
        int byte = ((rb << 7) + (ce << 1)) ^ ((rb & 7) << 4);
        bf16x8 kfr = *(const bf16x8*)(KsB + byte);
        s0 = mfma16(kfr, qf[0][kk], s0);
        s1 = mfma16(kfr, qf[1][kk], s1);
      }
      pk0[0][ni] = cvtpk(exp2f(s0[0]), exp2f(s0[1]));
      pk1[0][ni] = cvtpk(exp2f(s0[2]), exp2f(s0[3]));
      pk0[1][ni] = cvtpk(exp2f(s1[0]), exp2f(s1[1]));
      pk1[1][ni] = cvtpk(exp2f(s1[2]), exp2f(s1[3]));
    }

    // Build PV A-fragments in-register:
    // pa[mi][slot] elem t = P[q][slot*32 + 8*(lane>>4) + t]
    // permlane32_swap(x,y): x'=[x.r0,x.r1,y.r0,y.r1], y'=[x.r2,x.r3,y.r2,y.r3]
    // permlane16_swap(x,y): x'=[x.r0,y.r0,x.r2,y.r2], y'=[x.r1,y.r1,x.r3,y.r3]
    bf16x8 pa[2][2];
#pragma unroll
    for (int mi = 0; mi < 2; ++mi)
#pragma unroll
      for (int slot = 0; slot < 2; ++slot) {
        unsigned a0 = pk0[mi][2 * slot], a1 = pk0[mi][2 * slot + 1];
        asm("v_permlane32_swap_b32 %0, %1" : "+v"(a0), "+v"(a1));
        asm("v_permlane16_swap_b32 %0, %1" : "+v"(a0), "+v"(a1));
        unsigned b0 = pk1[mi][2 * slot], b1 = pk1[mi][2 * slot + 1];
        asm("v_permlane32_swap_b32 %0, %1" : "+v"(b0), "+v"(b1));
        asm("v_permlane16_swap_b32 %0, %1" : "+v"(b0), "+v"(b1));
        u32x4 pw = (u32x4){a0, b0, a1, b1};
        pa[mi][slot] = __builtin_bit_cast(bf16x8, pw);
      }

    // O += P V ; O_img += P V_img ; l += P @ ones
#pragma unroll
    for (int kk = 0; kk < 2; ++kk) {
      int co = kk * 32 + (lane >> 4) * 8;
      l_acc[0] = mfma16(pa[0][kk], onesf, l_acc[0]);
      l_acc[1] = mfma16(pa[1][kk], onesf, l_acc[1]);
#pragma unroll
      for (int nd = 0; nd < 4; ++nd) {
        int rv = nd * 16 + (lane & 15);
        int byte = ((rv << 7) + (co << 1)) ^ ((rv & 7) << 4);
        bf16x8 vb = *(const bf16x8*)(VsB + byte);
        bf16x8 vib = *(const bf16x8*)(VisB + byte);
        o_[0][nd] = mfma16(pa[0][kk], vb, o_[0][nd]);
        o_[1][nd] = mfma16(pa[1][kk], vb, o_[1][nd]);
        oi_[0][nd] = mfma16(pa[0][kk], vib, oi_[0][nd]);
        oi_[1][nd] = mfma16(pa[1][kk], vib, oi_[1][nd]);
      }
    }
    __syncthreads();
    buf ^= 1;
  }
#undef ATTN_STAGE

  // epilogue: divide by l, write HEAD-MAJOR [b,h,n,d] bf16 (dense 128B rows)
#pragma unroll
  for (int mi = 0; mi < 2; ++mi)
#pragma unroll
    for (int j = 0; j < 4; ++j) {
      float inv = 1.0f / l_acc[mi][j];
      int n_ = qt * 128 + w * 32 + mi * 16 + (lane >> 4) * 4 + j;
      size_t base = ((size_t)bh * NSEQ + n_) * HD;
#pragma unroll
      for (int nd = 0; nd < 4; ++nd) {
        int d_ = nd * 16 + (lane & 15);
        xo[base + d_] = f2bf1(o_[mi][nd][j] * inv);
        xio[base + d_] = f2bf1(oi_[mi][nd][j] * inv);
      }
    }
}

// ---------------- output projections (2-phase, R4 grid): out = X @ W^T + bias ----------------
// X is head-major [b,h,n,d]; K-tile kt == head kt, so A staging stays contiguous.
__global__ __launch_bounds__(256) void k_outproj(
    const short* __restrict__ xa, const short* __restrict__ xb,
    const short* __restrict__ wa, const short* __restrict__ wb,
    const float* __restrict__ ba, const float* __restrict__ bb,
    float* __restrict__ out) {
  __shared__ __align__(16) short SM[32768];   // As[2] | Bs[2]
  const int tid = threadIdx.x;
  const int lane = tid & 63;
  const int w = tid >> 6;
  const int wm = w >> 1, wn = w & 1;
  const int mt = blockIdx.x, nt = blockIdx.y, s = blockIdx.z;
  const short* X = (s == 0) ? xa : xb;
  const short* W = (s == 0) ? wa : wb;
  const float* bias = (s == 0) ? ba : bb;
  float* O = out + (size_t)s * SEG;

  f32x4 acc[4][4];
#pragma unroll
  for (int mi = 0; mi < 4; ++mi)
#pragma unroll
    for (int ni = 0; ni < 4; ++ni) acc[mi][ni] = (f32x4){0.f, 0.f, 0.f, 0.f};

#define OUTP_STAGE(BUF, KT) do { \
  _Pragma("unroll") for (int ii = 0; ii < 4; ++ii) { \
    int g = ii * 256 + tid; \
    int o = g * 16; \
    int r = o >> 7; \
    int c0 = ((o & 127) ^ ((r & 7) << 4)) >> 1; \
    int m = mt * 128 + r; \
    GLL16(X + (((size_t)(m >> 10) * NH + (KT)) * NSEQ + (m & 1023)) * HD + c0, \
          (char*)(SM + (BUF) * 8192) + o); \
    GLL16(W + (size_t)(nt * 128 + r) * DIMC + (KT) * 64 + c0, \
          (char*)(SM + 16384 + (BUF) * 8192) + o); \
  } \
} while (0)

  OUTP_STAGE(0, 0);
  __syncthreads();
  int buf = 0;
  for (int kt = 0; kt < 12; ++kt) {
    if (kt < 11) OUTP_STAGE(buf ^ 1, kt + 1);
    const char* As = (const char*)(SM + buf * 8192);
    const char* Bs = (const char*)(SM + 16384 + buf * 8192);
#pragma unroll
    for (int kk = 0; kk < 2; ++kk) {
      bf16x8 a[4], b[4];
      int ce = kk * 32 + (lane >> 4) * 8;
#pragma unroll
      for (int mi = 0; mi < 4; ++mi) {
        int ra = wm * 64 + mi * 16 + (lane & 15);
        int byte = ((ra << 7) + (ce << 1)) ^ ((ra & 7) << 4);
        a[mi] = *(const bf16x8*)(As + byte);
      }
#pragma unroll
      for (int ni = 0; ni < 4; ++ni) {
        int rb = wn * 64 + ni * 16 + (lane & 15);
        int byte = ((rb << 7) + (ce << 1)) ^ ((rb & 7) << 4);
        b[ni] = *(const bf16x8*)(Bs + byte);
      }
#pragma unroll
      for (int mi = 0; mi < 4; ++mi)
#pragma unroll
        for (int ni = 0; ni < 4; ++ni)
          acc[mi][ni] = mfma16(a[mi], b[ni], acc[mi][ni]);
    }
    __syncthreads();
    buf ^= 1;
  }
#undef OUTP_STAGE

#pragma unroll
  for (int mi = 0; mi < 4; ++mi)
#pragma unroll
    for (int ni = 0; ni < 4; ++ni)
#pragma unroll
      for (int j = 0; j < 4; ++j) {
        int m = mt * 128 + wm * 64 + mi * 16 + (lane >> 4) * 4 + j;
        int dc = nt * 128 + wn * 64 + ni * 16 + (lane & 15);
        O[(size_t)m * DIMC + dc] = acc[mi][ni][j] + bias[dc];
      }
}

extern "C" void kernel_launch(void* const* d_in, const int* in_sizes, int n_in,
                              void* d_out, int out_size, void* d_ws, size_t ws_size,
                              hipStream_t stream) {
  (void)in_sizes; (void)n_in; (void)out_size; (void)ws_size;
  const float* q    = (const float*)d_in[0];
  const float* k    = (const float*)d_in[1];
  const float* v    = (const float*)d_in[2];
  const float* vimg = (const float*)d_in[3];
  const float* Wq   = (const float*)d_in[4];
  const float* Wk   = (const float*)d_in[5];
  const float* Wv   = (const float*)d_in[6];
  const float* Wvim = (const float*)d_in[7];
  const float* Wp   = (const float*)d_in[8];
  const float* bp   = (const float*)d_in[9];
  const float* Wpi  = (const float*)d_in[10];
  const float* bpi  = (const float*)d_in[11];

  short* ws = (short*)d_ws;
  short* xq  = ws;
  short* xk  = ws + (size_t)SEG;
  short* xv  = ws + (size_t)2 * SEG;
  short* xvi = ws + (size_t)3 * SEG;
  short* wqb  = ws + (size_t)4 * SEG;
  short* wkb  = wqb + WSEG;
  short* wvb  = wkb + WSEG;
  short* wvib = wvb + WSEG;
  short* wpb  = wvib + WSEG;
  short* wpib = wpb + WSEG;
  short* qh  = ws + (size_t)4 * SEG + 6 * (size_t)WSEG;
  short* kh  = qh + (size_t)SEG;
  short* vht = kh + (size_t)SEG;    // V transposed [b,h,d,n]
  short* viht = vht + (size_t)SEG;  // V_img transposed
  short* xo  = viht + (size_t)SEG;  // attn out, head-major [b,h,n,d]
  short* xio = xo + (size_t)SEG;

  const float SCL2E = 0.125f * 1.44269504f;   // attention scale * log2(e), folded into Wq

  // 1) convert to bf16 (Wq pre-scaled)
  k_cvt4<<<dim3(SEG / 4 / 256, 4), 256, 0, stream>>>(q, k, v, vimg, xq, xk, xv, xvi, SEG / 4,
                                                     1.f, 1.f, 1.f, 1.f);
  k_cvt4<<<dim3(WSEG / 4 / 256, 4), 256, 0, stream>>>(Wq, Wk, Wv, Wvim, wqb, wkb, wvb, wvib, WSEG / 4,
                                                      SCL2E, 1.f, 1.f, 1.f);
  k_cvt4<<<dim3(WSEG / 4 / 256, 2), 256, 0, stream>>>(Wp, Wpi, Wp, Wpi, wpb, wpib, wpb, wpib, WSEG / 4,
                                                      1.f, 1.f, 1.f, 1.f);

  // 2) input projections: Q,K -> [b,h,n,d]; V,Vi -> [b,h,d,n]  (R4 grid: mt fastest)
  k_proj<<<dim3(64, 6, 4), 256, 0, stream>>>(xq, xk, xv, xvi, wqb, wkb, wvb, wvib, qh, kh, vht, viht);

  // 3) shared-softmax attention, two value streams -> head-major [b,h,n,d] bf16
  k_attn<<<dim3(768), 256, 0, stream>>>(qh, kh, vht, viht, xo, xio);

  // 4) output projections + bias -> fp32 d_out (x then x_im)  (R4 grid: mt fastest)
  k_outproj<<<dim3(64, 6, 2), 256, 0, stream>>>(xo, xio, wpb, wpib, bp, bpi, (float*)d_out);
}